// Round 5
// baseline (755.897 us; speedup 1.0000x reference)
//
#include <hip/hip_runtime.h>
#include <hip/hip_bf16.h>
#include <math.h>

// Problem constants
#define BB 8
#define CC 64
#define NN 4096
#define CO 64
#define KK 20
#define BN (BB*NN)           // 32768 rows
#define CN (CC*NN)           // 262144
#define EPSV 1e-5
#define NEG_SLOPE 0.2f
#define CNT_TOTAL 655360.0   // B*N*K
#define CAP 64
#define MARGIN 0.02f

typedef unsigned short U16;
typedef unsigned int u32;
typedef unsigned long long u64;
typedef __attribute__((ext_vector_type(8))) __bf16 bf16x8;
typedef __attribute__((ext_vector_type(16))) float f32x16;

// Workspace layout (bytes)
#define OFF_P1    ((size_t)0)          // BN*64 f32 = 8388608
#define OFF_P2    ((size_t)8388608)
#define OFF_XX    ((size_t)16777216)   // BN f32
#define OFF_IDX   ((size_t)16908288)   // BN*20 i32
#define OFF_XT    ((size_t)19529728)   // BN*64 f32 row-major points
#define OFF_XH    ((size_t)27918336)   // BN*64 bf16 hi
#define OFF_XL    ((size_t)32112640)   // BN*64 bf16 lo
#define OFF_TV    ((size_t)36306944)   // BN*4*20 f32 partial top-20 values
#define OFF_THR   ((size_t)46792704)   // BN f32
#define OFF_CAND  ((size_t)46923776)   // BN*CAP i32
#define OFF_CCNT  ((size_t)55312384)   // BN i32 (zeroed)
#define OFF_MAXH  ((size_t)55443456)
#define OFF_MINH  ((size_t)63832064)
#define OFF_SUMS  ((size_t)72220672)   // 128 f64 (zeroed)

// sorted-desc insert; with invariant tv[q-1] >= tv[q], max(min(hi,d),lo) == med3(hi,d,lo)
#define NET_INS(dv) { const float d_ = (dv); _Pragma("unroll") \
  for (int q_ = KK-1; q_ >= 1; --q_) tv[q_] = __builtin_amdgcn_fmed3f(tv[q_-1], d_, tv[q_]); \
  tv[0] = fmaxf(tv[0], d_); }

// ---------------- K0: transpose x -> XT f32 [B][N][64], split bf16 hi/lo
__global__ __launch_bounds__(256) void k0_repack(
    const float* __restrict__ x, float* __restrict__ XT,
    U16* __restrict__ XH, U16* __restrict__ XL) {
  __shared__ float tile[64*65];
  const int b = blockIdx.y, n0 = blockIdx.x*64, t = threadIdx.x;
#pragma unroll
  for (int r = 0; r < 16; ++r) {
    const int c = r*4 + (t>>6);
    const int nn = t & 63;
    tile[c*65 + nn] = x[(size_t)b*CN + (size_t)c*NN + n0 + nn];
  }
  __syncthreads();
  const int g = t>>6, pos = t&63;
  float v[16];
#pragma unroll
  for (int cc = 0; cc < 16; ++cc) v[cc] = tile[(g*16+cc)*65 + pos];
  const size_t base = ((size_t)(b*NN + n0 + pos))*64 + g*16;
#pragma unroll
  for (int u = 0; u < 4; ++u)
    *(float4*)(XT + base + u*4) = make_float4(v[u*4],v[u*4+1],v[u*4+2],v[u*4+3]);
  U16 hb[16], lb[16];
#pragma unroll
  for (int cc = 0; cc < 16; ++cc) {
    __hip_bfloat16 h = __float2bfloat16(v[cc]);
    float hf = __bfloat162float(h);
    __hip_bfloat16 lo = __float2bfloat16(v[cc] - hf);
    hb[cc] = reinterpret_cast<U16&>(h);
    lb[cc] = reinterpret_cast<U16&>(lo);
  }
  uint hw[8], lw[8];
#pragma unroll
  for (int u = 0; u < 8; ++u) {
    hw[u] = (uint)hb[2*u] | ((uint)hb[2*u+1] << 16);
    lw[u] = (uint)lb[2*u] | ((uint)lb[2*u+1] << 16);
  }
  *(uint4*)(XH + base)     = make_uint4(hw[0],hw[1],hw[2],hw[3]);
  *(uint4*)(XH + base + 8) = make_uint4(hw[4],hw[5],hw[6],hw[7]);
  *(uint4*)(XL + base)     = make_uint4(lw[0],lw[1],lw[2],lw[3]);
  *(uint4*)(XL + base + 8) = make_uint4(lw[4],lw[5],lw[6],lw[7]);
}

// ---------------- K1: projections p1=(W1-W2)x, p2=W2 x, xx=|x|^2
__global__ __launch_bounds__(256) void k1_project(
    const float* __restrict__ x, const float* __restrict__ W,
    float* __restrict__ p1, float* __restrict__ p2, float* __restrict__ xx) {
  const int b  = blockIdx.y;
  const int n0 = blockIdx.x * 64;
  const int t  = threadIdx.x;
  const int pos = t & 63, og = t >> 6;
  const int n = n0 + pos;
  const float* xb = x + (size_t)b*CN + n;

  float a1[16], a2[16];
#pragma unroll
  for (int i = 0; i < 16; ++i) { a1[i] = 0.f; a2[i] = 0.f; }
  float xxa = 0.f;
#pragma unroll
  for (int c4 = 0; c4 < 16; ++c4) {
    float xv[4];
#pragma unroll
    for (int u = 0; u < 4; ++u) xv[u] = xb[(size_t)(c4*4+u)*NN];
    if (og == 0) xxa += xv[0]*xv[0] + xv[1]*xv[1] + xv[2]*xv[2] + xv[3]*xv[3];
#pragma unroll
    for (int oi = 0; oi < 16; ++oi) {
      const int o = og*16 + oi;
      const float4 w1 = *(const float4*)(W + o*128 + c4*4);
      const float4 w2 = *(const float4*)(W + o*128 + 64 + c4*4);
      a1[oi] += (w1.x - w2.x)*xv[0] + (w1.y - w2.y)*xv[1]
              + (w1.z - w2.z)*xv[2] + (w1.w - w2.w)*xv[3];
      a2[oi] += w2.x*xv[0] + w2.y*xv[1] + w2.z*xv[2] + w2.w*xv[3];
    }
  }
  float* p1o = p1 + ((size_t)(b*NN + n))*64 + og*16;
  float* p2o = p2 + ((size_t)(b*NN + n))*64 + og*16;
#pragma unroll
  for (int oi = 0; oi < 16; ++oi) { p1o[oi] = a1[oi]; p2o[oi] = a2[oi]; }
  if (og == 0) xx[b*NN + n] = xxa;
}

// ---------------- K2ab: MFMA Gram; MODE0 = top-20 values, MODE1 = collect
template<int MODE>
__global__ __launch_bounds__(256, 2) void k2ab(
    const U16* __restrict__ XH, const U16* __restrict__ XL,
    const float* __restrict__ xx, float* __restrict__ TV,
    const float* __restrict__ thr, int* __restrict__ ccnt,
    int* __restrict__ cand) {
  __shared__ float sc[256*36];   // scores [256 rows][32 cols], stride 36 (MODE0)
  __shared__ float xxs[1024];    // xx_j for this q-range
  __shared__ float thrs[256];    // thr for this row-block (MODE1)
  const int b = blockIdx.z, q = blockIdx.y, i0 = blockIdx.x*256;
  const int t = threadIdx.x, w = t>>6, l = t&63, lo5 = l&31, hi5 = l>>5;
  const int ch0 = 8*hi5;
  const int rowg = b*NN + i0 + t;
  const size_t bnn = (size_t)b*NN;
  const int jbase = q*1024;

  *(float4*)(xxs + t*4) = *(const float4*)(xx + bnn + jbase + t*4);
  if constexpr (MODE == 1) thrs[t] = thr[rowg];
  __syncthreads();

  // hoist A fragments for the whole block lifetime
  bf16x8 Ah[2][4], Al[2][4];
  const size_t abase = (bnn + i0 + w*64 + lo5)*64 + ch0;
#pragma unroll
  for (int ms = 0; ms < 2; ++ms)
#pragma unroll
    for (int ks = 0; ks < 4; ++ks) {
      Ah[ms][ks] = *(const bf16x8*)(XH + abase + ms*2048 + ks*16);
      Al[ms][ks] = *(const bf16x8*)(XL + abase + ms*2048 + ks*16);
    }

  float tv[KK];
  float thrR[2][16];
  if constexpr (MODE == 0) {
#pragma unroll
    for (int k = 0; k < KK; ++k) tv[k] = -INFINITY;
  } else {
#pragma unroll
    for (int ms = 0; ms < 2; ++ms)
#pragma unroll
      for (int r = 0; r < 16; ++r)
        thrR[ms][r] = thrs[w*64 + ms*32 + (r&3) + 8*(r>>2) + 4*hi5];
  }

  auto loadB = [&](int chunk, bf16x8* Bh, bf16x8* Bl) {
    const size_t bfb = (bnn + jbase + chunk*32 + lo5)*64 + ch0;
#pragma unroll
    for (int ks = 0; ks < 4; ++ks) {
      Bh[ks] = *(const bf16x8*)(XH + bfb + ks*16);
      Bl[ks] = *(const bf16x8*)(XL + bfb + ks*16);
    }
  };

  auto dochunk = [&](int chunk, bf16x8* Bh, bf16x8* Bl) {
    f32x16 accP[2], accQ[2];
#pragma unroll
    for (int ms = 0; ms < 2; ++ms)
#pragma unroll
      for (int r = 0; r < 16; ++r) { accP[ms][r] = 0.f; accQ[ms][r] = 0.f; }
#pragma unroll
    for (int ks = 0; ks < 4; ++ks)
#pragma unroll
      for (int ms = 0; ms < 2; ++ms) {
        accP[ms] = __builtin_amdgcn_mfma_f32_32x32x16_bf16(Ah[ms][ks], Bh[ks], accP[ms], 0,0,0);
        accQ[ms] = __builtin_amdgcn_mfma_f32_32x32x16_bf16(Ah[ms][ks], Bl[ks], accQ[ms], 0,0,0);
        accQ[ms] = __builtin_amdgcn_mfma_f32_32x32x16_bf16(Al[ms][ks], Bh[ks], accQ[ms], 0,0,0);
      }
    if constexpr (MODE == 0) {
      __syncthreads();   // prev scan done
#pragma unroll
      for (int ms = 0; ms < 2; ++ms)
#pragma unroll
        for (int r = 0; r < 16; ++r) {
          const int lrow = w*64 + ms*32 + (r&3) + 8*(r>>2) + 4*hi5;
          sc[lrow*36 + lo5] = accP[ms][r] + accQ[ms][r];
        }
      __syncthreads();
      const float* rowp = sc + t*36;
      const float* xxp = xxs + chunk*32;
#pragma unroll
      for (int c4 = 0; c4 < 8; ++c4) {
        const float4 v = *(const float4*)(rowp + c4*4);
        NET_INS(2.f*v.x - xxp[c4*4+0])
        NET_INS(2.f*v.y - xxp[c4*4+1])
        NET_INS(2.f*v.z - xxp[c4*4+2])
        NET_INS(2.f*v.w - xxp[c4*4+3])
      }
    } else {
      const float xxj = xxs[chunk*32 + lo5];
      const int j = jbase + chunk*32 + lo5;
#pragma unroll
      for (int ms = 0; ms < 2; ++ms)
#pragma unroll
        for (int r = 0; r < 16; ++r) {
          const float d = 2.f*(accP[ms][r] + accQ[ms][r]) - xxj;
          if (d >= thrR[ms][r]) {
            const int rg = b*NN + i0 + w*64 + ms*32 + (r&3) + 8*(r>>2) + 4*hi5;
            const int pos = atomicAdd(&ccnt[rg], 1);
            if (pos < CAP) cand[(size_t)rg*CAP + pos] = j;
          }
        }
    }
  };

  // software pipeline: explicit even/odd B-fragment double buffer
  bf16x8 BhE[4], BlE[4], BhO[4], BlO[4];
  loadB(0, BhE, BlE);
  for (int c2 = 0; c2 < 16; ++c2) {
    loadB(2*c2+1, BhO, BlO);
    dochunk(2*c2, BhE, BlE);
    if (c2 < 15) loadB(2*c2+2, BhE, BlE);
    dochunk(2*c2+1, BhO, BlO);
  }

  if constexpr (MODE == 0) {
#pragma unroll
    for (int k = 0; k < KK; ++k) TV[((size_t)rowg*4 + q)*KK + k] = tv[k];
  }
}

// ---------------- K2b: 20th-largest of 4x20 partials -> thr = t19 - margin
__global__ __launch_bounds__(256) void k2b_thr(
    const float* __restrict__ TV, float* __restrict__ thr) {
  const int rowg = blockIdx.x*256 + threadIdx.x;
  float tv[KK];
#pragma unroll
  for (int k = 0; k < KK; ++k) tv[k] = -INFINITY;
  const float* p = TV + (size_t)rowg*80;
#pragma unroll
  for (int u = 0; u < 20; ++u) {
    const float4 v = *(const float4*)(p + u*4);
    NET_INS(v.x) NET_INS(v.y) NET_INS(v.z) NET_INS(v.w)
  }
  thr[rowg] = tv[KK-1] - MARGIN;
}

// ---------------- K2e: exact f32 dots on candidates, top-20 with numpy ties
__global__ __launch_bounds__(256) void k2e_exact(
    const float* __restrict__ XT, const float* __restrict__ xx,
    const int* __restrict__ ccnt, const int* __restrict__ cand,
    int* __restrict__ idxo) {
  const int t = threadIdx.x, w = t>>6, l = t&63;
  const int rowg = blockIdx.x*64 + w*16 + (l>>2);
  const int g = l & 3;
  const int bbase = (rowg >> 12) << 12;   // b*NN
  const float* xip = XT + (size_t)rowg*64 + g*16;
  const float4 xi0 = *(const float4*)(xip),   xi1 = *(const float4*)(xip+4);
  const float4 xi2 = *(const float4*)(xip+8), xi3 = *(const float4*)(xip+12);
  const float xxi = xx[rowg];
  const int Cr = min(ccnt[rowg], CAP);
  int cmax = Cr;
#pragma unroll
  for (int off = 1; off < 64; off <<= 1) cmax = max(cmax, __shfl_xor(cmax, off));
  u64 kv[KK];
#pragma unroll
  for (int k = 0; k < KK; ++k) kv[k] = 0ULL;

  for (int c = 0; c < cmax; ++c) {
    const bool valid = (c < Cr);
    const int jj = valid ? cand[(size_t)rowg*CAP + c] : 0;
    const float* xjp = XT + ((size_t)(bbase + jj))*64 + g*16;
    const float4 a  = *(const float4*)(xjp),   b4 = *(const float4*)(xjp+4);
    const float4 c4 = *(const float4*)(xjp+8), d4 = *(const float4*)(xjp+12);
    float p = xi0.x*a.x;
    p = fmaf(xi0.y, a.y, p);  p = fmaf(xi0.z, a.z, p);  p = fmaf(xi0.w, a.w, p);
    p = fmaf(xi1.x, b4.x, p); p = fmaf(xi1.y, b4.y, p); p = fmaf(xi1.z, b4.z, p); p = fmaf(xi1.w, b4.w, p);
    p = fmaf(xi2.x, c4.x, p); p = fmaf(xi2.y, c4.y, p); p = fmaf(xi2.z, c4.z, p); p = fmaf(xi2.w, c4.w, p);
    p = fmaf(xi3.x, d4.x, p); p = fmaf(xi3.y, d4.y, p); p = fmaf(xi3.z, d4.z, p); p = fmaf(xi3.w, d4.w, p);
    p += __shfl_xor(p, 1);
    p += __shfl_xor(p, 2);
    const float d = 2.f*p - xxi - xx[bbase + jj];
    const u32 s = __float_as_uint(d);
    const u32 k32 = (s & 0x80000000u) ? ~s : (s | 0x80000000u);
    u64 key = ((u64)k32 << 32) | (u64)(0xFFFFFFFFu - (u32)jj);
    if (!valid) key = 0ULL;
#pragma unroll
    for (int qq = KK-1; qq >= 1; --qq) {
      const u64 mn = (kv[qq-1] < key) ? kv[qq-1] : key;
      if (kv[qq] < mn) kv[qq] = mn;
    }
    if (kv[0] < key) kv[0] = key;
  }
  if (g == 0) {
#pragma unroll
    for (int k = 0; k < KK; ++k)
      idxo[(size_t)rowg*KK + k] = (int)(0xFFFFFFFFu - (u32)(kv[k] & 0xFFFFFFFFu));
  }
}

// ---------------- K3: gather neighbors, per-(b,n,o) max/min of h, BN sums
__global__ __launch_bounds__(256) void k3_gather(
    const float* __restrict__ p1, const float* __restrict__ p2,
    const int* __restrict__ idx, float* __restrict__ maxh,
    float* __restrict__ minh, double* __restrict__ sums) {
  const int t = threadIdx.x;
  const int g = t >> 6, o = t & 63;
  const int pn0 = blockIdx.x*64 + g*16;
  float sacc = 0.f, ssacc = 0.f;

  for (int p = 0; p < 16; ++p) {
    const int pn = pn0 + p;
    const int bbase = (pn >> 12) << 12;
    const float p1v = p1[(size_t)pn*64 + o];
    const int* ip = idx + (size_t)pn*KK;
    float mx = -INFINITY, mn = INFINITY;
#pragma unroll
    for (int k = 0; k < KK; ++k) {
      const int j = ip[k];
      const float p2v = p2[((size_t)(bbase + j))*64 + o];
      const float h = p1v + p2v;
      mx = fmaxf(mx, h); mn = fminf(mn, h);
      sacc += h; ssacc += h*h;
    }
    maxh[(size_t)pn*64 + o] = mx;
    minh[(size_t)pn*64 + o] = mn;
  }

  __shared__ float rs[256], rss[256];
  rs[t] = sacc; rss[t] = ssacc;
  __syncthreads();
  if (t < 64) {
    const double sv  = (double)rs[t]  + (double)rs[t+64]  + (double)rs[t+128]  + (double)rs[t+192];
    const double ssv = (double)rss[t] + (double)rss[t+64] + (double)rss[t+128] + (double)rss[t+192];
    atomicAdd(&sums[t], sv);
    atomicAdd(&sums[64 + t], ssv);
  }
}

// ---------------- K4: finalize BN, activation, transpose to (b,o,n)
__global__ __launch_bounds__(256) void k4_out(
    const float* __restrict__ maxh, const float* __restrict__ minh,
    const double* __restrict__ sums, const float* __restrict__ gamma,
    const float* __restrict__ beta, float* __restrict__ out) {
  __shared__ float sc_[64], sh_[64];
  __shared__ float lmax[64*65], lmin[64*65];
  const int b  = blockIdx.y;
  const int n0 = blockIdx.x * 64;
  const int t  = threadIdx.x;

  if (t < 64) {
    const double mean = sums[t] / CNT_TOTAL;
    const double var  = sums[64 + t] / CNT_TOTAL - mean*mean;
    const float scale = gamma[t] * (float)(1.0 / sqrt(var + EPSV));
    sc_[t] = scale;
    sh_[t] = beta[t] - (float)mean * scale;
  }
#pragma unroll
  for (int r = 0; r < 16; ++r) {
    const int linear = r*256 + t;
    const int o = linear & 63, pos = linear >> 6;
    const size_t gg = ((size_t)(b*NN) + n0 + pos)*64 + o;
    lmax[o*65 + pos] = maxh[gg];
    lmin[o*65 + pos] = minh[gg];
  }
  __syncthreads();

  const int nn = t & 63;
  const int obase = (t >> 6) * 16;
#pragma unroll
  for (int r = 0; r < 16; ++r) {
    const int o = obase + r;
    const float scale = sc_[o], shift = sh_[o];
    const float src = (scale >= 0.f) ? lmax[o*65 + nn] : lmin[o*65 + nn];
    float v = scale*src + shift;
    v = (v >= 0.f) ? v : NEG_SLOPE*v;
    out[(size_t)b*CO*NN + (size_t)o*NN + n0 + nn] = v;
  }
}

extern "C" void kernel_launch(void* const* d_in, const int* in_sizes, int n_in,
                              void* d_out, int out_size, void* d_ws, size_t ws_size,
                              hipStream_t stream) {
  const float* x     = (const float*)d_in[0];
  const float* W     = (const float*)d_in[1];
  const float* gamma = (const float*)d_in[2];
  const float* beta  = (const float*)d_in[3];
  float* out = (float*)d_out;
  char* ws = (char*)d_ws;

  float*  p1   = (float*)(ws + OFF_P1);
  float*  p2   = (float*)(ws + OFF_P2);
  float*  xx   = (float*)(ws + OFF_XX);
  int*    idx  = (int*)  (ws + OFF_IDX);
  float*  XT   = (float*)(ws + OFF_XT);
  U16*    XH   = (U16*)  (ws + OFF_XH);
  U16*    XL   = (U16*)  (ws + OFF_XL);
  float*  TV   = (float*)(ws + OFF_TV);
  float*  thr  = (float*)(ws + OFF_THR);
  int*    cand = (int*)  (ws + OFF_CAND);
  int*    ccnt = (int*)  (ws + OFF_CCNT);
  float*  maxh = (float*)(ws + OFF_MAXH);
  float*  minh = (float*)(ws + OFF_MINH);
  double* sums = (double*)(ws + OFF_SUMS);

  hipMemsetAsync(ws + OFF_CCNT, 0, BN*sizeof(int), stream);
  hipMemsetAsync(ws + OFF_SUMS, 0, 128*sizeof(double), stream);

  k0_repack <<<dim3(NN/64, BB), 256, 0, stream>>>(x, XT, XH, XL);
  k1_project<<<dim3(NN/64, BB), 256, 0, stream>>>(x, W, p1, p2, xx);
  k2ab<0>   <<<dim3(NN/256, 4, BB), 256, 0, stream>>>(XH, XL, xx, TV, thr, ccnt, cand);
  k2b_thr   <<<dim3(BN/256), 256, 0, stream>>>(TV, thr);
  k2ab<1>   <<<dim3(NN/256, 4, BB), 256, 0, stream>>>(XH, XL, xx, TV, thr, ccnt, cand);
  k2e_exact <<<dim3(BN/64), 256, 0, stream>>>(XT, xx, ccnt, cand, idx);
  k3_gather <<<dim3(BN/64), 256, 0, stream>>>(p1, p2, idx, maxh, minh, sums);
  k4_out    <<<dim3(NN/64, BB), 256, 0, stream>>>(maxh, minh, sums, gamma, beta, out);
}

// Round 6
// 691.681 us; speedup vs baseline: 1.0928x; 1.0928x over previous
//
#include <hip/hip_runtime.h>
#include <hip/hip_bf16.h>
#include <math.h>

// Problem constants
#define BB 8
#define CC 64
#define NN 4096
#define CO 64
#define KK 20
#define BN (BB*NN)           // 32768 rows
#define CN (CC*NN)           // 262144
#define EPSV 1e-5
#define NEG_SLOPE 0.2f
#define CNT_TOTAL 655360.0   // B*N*K
#define CAP 64
#define MARGIN 0.02f

typedef unsigned short U16;
typedef unsigned int u32;
typedef unsigned long long u64;
typedef __attribute__((ext_vector_type(8))) __bf16 bf16x8;
typedef __attribute__((ext_vector_type(16))) float f32x16;

// Workspace layout (bytes). MAXH/MINH alias TV (TV dead after k2b).
#define OFF_P1    ((size_t)0)
#define OFF_P2    ((size_t)8388608)
#define OFF_XX    ((size_t)16777216)
#define OFF_IDX   ((size_t)16908288)
#define OFF_XT    ((size_t)19529728)
#define OFF_XH    ((size_t)27918336)
#define OFF_XL    ((size_t)32112640)
#define OFF_TV    ((size_t)36306944)   // BN*8*20 f32 = 20971520
#define OFF_THR   ((size_t)57278464)
#define OFF_CAND  ((size_t)57409536)   // BN*CAP i32
#define OFF_CCNT  ((size_t)65798144)   // zeroed
#define OFF_SUMS  ((size_t)65929216)   // zeroed (adjacent to CCNT)
#define OFF_MAXH  ((size_t)36306944)   // alias TV
#define OFF_MINH  ((size_t)44695552)

// sorted-desc insert; invariant tv[q-1]>=tv[q] -> max(min(hi,d),lo) == med3
#define NET_INS(dv) { const float d_ = (dv); _Pragma("unroll") \
  for (int q_ = KK-1; q_ >= 1; --q_) tv[q_] = __builtin_amdgcn_fmed3f(tv[q_-1], d_, tv[q_]); \
  tv[0] = fmaxf(tv[0], d_); }

// ---------------- K0: transpose x -> XT f32 [B][N][64], split bf16 hi/lo
__global__ __launch_bounds__(256) void k0_repack(
    const float* __restrict__ x, float* __restrict__ XT,
    U16* __restrict__ XH, U16* __restrict__ XL) {
  __shared__ float tile[64*65];
  const int b = blockIdx.y, n0 = blockIdx.x*64, t = threadIdx.x;
#pragma unroll
  for (int r = 0; r < 16; ++r) {
    const int c = r*4 + (t>>6);
    const int nn = t & 63;
    tile[c*65 + nn] = x[(size_t)b*CN + (size_t)c*NN + n0 + nn];
  }
  __syncthreads();
  const int g = t>>6, pos = t&63;
  float v[16];
#pragma unroll
  for (int cc = 0; cc < 16; ++cc) v[cc] = tile[(g*16+cc)*65 + pos];
  const size_t base = ((size_t)(b*NN + n0 + pos))*64 + g*16;
#pragma unroll
  for (int u = 0; u < 4; ++u)
    *(float4*)(XT + base + u*4) = make_float4(v[u*4],v[u*4+1],v[u*4+2],v[u*4+3]);
  U16 hb[16], lb[16];
#pragma unroll
  for (int cc = 0; cc < 16; ++cc) {
    __hip_bfloat16 h = __float2bfloat16(v[cc]);
    float hf = __bfloat162float(h);
    __hip_bfloat16 lo = __float2bfloat16(v[cc] - hf);
    hb[cc] = reinterpret_cast<U16&>(h);
    lb[cc] = reinterpret_cast<U16&>(lo);
  }
  uint hw[8], lw[8];
#pragma unroll
  for (int u = 0; u < 8; ++u) {
    hw[u] = (uint)hb[2*u] | ((uint)hb[2*u+1] << 16);
    lw[u] = (uint)lb[2*u] | ((uint)lb[2*u+1] << 16);
  }
  *(uint4*)(XH + base)     = make_uint4(hw[0],hw[1],hw[2],hw[3]);
  *(uint4*)(XH + base + 8) = make_uint4(hw[4],hw[5],hw[6],hw[7]);
  *(uint4*)(XL + base)     = make_uint4(lw[0],lw[1],lw[2],lw[3]);
  *(uint4*)(XL + base + 8) = make_uint4(lw[4],lw[5],lw[6],lw[7]);
}

// ---------------- K1: projections p1=(W1-W2)x, p2=W2 x, xx=|x|^2
__global__ __launch_bounds__(256) void k1_project(
    const float* __restrict__ x, const float* __restrict__ W,
    float* __restrict__ p1, float* __restrict__ p2, float* __restrict__ xx) {
  const int b  = blockIdx.y;
  const int n0 = blockIdx.x * 64;
  const int t  = threadIdx.x;
  const int pos = t & 63, og = t >> 6;
  const int n = n0 + pos;
  const float* xb = x + (size_t)b*CN + n;

  float a1[16], a2[16];
#pragma unroll
  for (int i = 0; i < 16; ++i) { a1[i] = 0.f; a2[i] = 0.f; }
  float xxa = 0.f;
#pragma unroll
  for (int c4 = 0; c4 < 16; ++c4) {
    float xv[4];
#pragma unroll
    for (int u = 0; u < 4; ++u) xv[u] = xb[(size_t)(c4*4+u)*NN];
    if (og == 0) xxa += xv[0]*xv[0] + xv[1]*xv[1] + xv[2]*xv[2] + xv[3]*xv[3];
#pragma unroll
    for (int oi = 0; oi < 16; ++oi) {
      const int o = og*16 + oi;
      const float4 w1 = *(const float4*)(W + o*128 + c4*4);
      const float4 w2 = *(const float4*)(W + o*128 + 64 + c4*4);
      a1[oi] += (w1.x - w2.x)*xv[0] + (w1.y - w2.y)*xv[1]
              + (w1.z - w2.z)*xv[2] + (w1.w - w2.w)*xv[3];
      a2[oi] += w2.x*xv[0] + w2.y*xv[1] + w2.z*xv[2] + w2.w*xv[3];
    }
  }
  float* p1o = p1 + ((size_t)(b*NN + n))*64 + og*16;
  float* p2o = p2 + ((size_t)(b*NN + n))*64 + og*16;
#pragma unroll
  for (int oi = 0; oi < 16; ++oi) { p1o[oi] = a1[oi]; p2o[oi] = a2[oi]; }
  if (og == 0) xx[b*NN + n] = xxa;
}

// ---------------- K2ab: MFMA Gram; MODE0 = top-20 values, MODE1 = collect
// 1D grid 1024: b = L&7 (XCD pin), q = (L>>3)&3, bx = L>>5. Block = 128 rows,
// wave = 32 rows (1 msub): A 32 + acc 32 + Bdbuf 64 + tv/thr ~20 regs.
template<int MODE>
__global__ __launch_bounds__(256, 3) void k2ab(
    const U16* __restrict__ XH, const U16* __restrict__ XL,
    const float* __restrict__ xx, float* __restrict__ TV,
    const float* __restrict__ thr, int* __restrict__ ccnt,
    int* __restrict__ cand) {
  __shared__ float sc[128*33];   // MODE0 score tile (stride 33: conflict-free)
  __shared__ float xxs[1024];
  __shared__ float thrs[128];
  const int L = blockIdx.x;
  const int b = L & 7, q = (L >> 3) & 3, bx = L >> 5;
  const int i0 = bx * 128;
  const int t = threadIdx.x, w = t>>6, l = t&63, lo5 = l&31, hi5 = l>>5;
  const int ch0 = 8*hi5;
  const size_t bnn = (size_t)b*NN;
  const int jbase = q*1024;

  *(float4*)(xxs + t*4) = *(const float4*)(xx + bnn + jbase + t*4);
  if constexpr (MODE == 1) { if (t < 128) thrs[t] = thr[bnn + i0 + t]; }
  __syncthreads();

  // A fragments: wave w owns rows i0 + w*32 + [0,32)
  bf16x8 Ah[4], Al[4];
  const size_t abase = (bnn + i0 + w*32 + lo5)*64 + ch0;
#pragma unroll
  for (int ks = 0; ks < 4; ++ks) {
    Ah[ks] = *(const bf16x8*)(XH + abase + ks*16);
    Al[ks] = *(const bf16x8*)(XL + abase + ks*16);
  }

  float tv[KK];
  float thrR[16];
  if constexpr (MODE == 0) {
#pragma unroll
    for (int k = 0; k < KK; ++k) tv[k] = -INFINITY;
  } else {
#pragma unroll
    for (int r = 0; r < 16; ++r)
      thrR[r] = thrs[w*32 + (r&3) + 8*(r>>2) + 4*hi5];
  }

  auto loadB = [&](int chunk, bf16x8* Bh, bf16x8* Bl) {
    const size_t bfb = (bnn + jbase + chunk*32 + lo5)*64 + ch0;
#pragma unroll
    for (int ks = 0; ks < 4; ++ks) {
      Bh[ks] = *(const bf16x8*)(XH + bfb + ks*16);
      Bl[ks] = *(const bf16x8*)(XL + bfb + ks*16);
    }
  };

  auto dochunk = [&](int chunk, bf16x8* Bh, bf16x8* Bl) {
    f32x16 accP, accQ;
#pragma unroll
    for (int r = 0; r < 16; ++r) { accP[r] = 0.f; accQ[r] = 0.f; }
#pragma unroll
    for (int ks = 0; ks < 4; ++ks) {
      accP = __builtin_amdgcn_mfma_f32_32x32x16_bf16(Ah[ks], Bh[ks], accP, 0,0,0);
      accQ = __builtin_amdgcn_mfma_f32_32x32x16_bf16(Ah[ks], Bl[ks], accQ, 0,0,0);
      accQ = __builtin_amdgcn_mfma_f32_32x32x16_bf16(Al[ks], Bh[ks], accQ, 0,0,0);
    }
    if constexpr (MODE == 0) {
      __syncthreads();   // prev scan done
#pragma unroll
      for (int r = 0; r < 16; ++r) {
        const int lrow = w*32 + (r&3) + 8*(r>>2) + 4*hi5;
        sc[lrow*33 + lo5] = accP[r] + accQ[r];
      }
      __syncthreads();
      const int row = t & 127, colh = t >> 7;
      const float* rowp = sc + row*33 + colh*16;
      const float* xxp = xxs + chunk*32 + colh*16;
#pragma unroll
      for (int cc = 0; cc < 16; ++cc) NET_INS(2.f*rowp[cc] - xxp[cc])
    } else {
      const float xxj = xxs[chunk*32 + lo5];
      const int j = jbase + chunk*32 + lo5;
#pragma unroll
      for (int r = 0; r < 16; ++r) {
        const float d = 2.f*(accP[r] + accQ[r]) - xxj;
        if (d >= thrR[r]) {
          const int rg = (int)bnn + i0 + w*32 + (r&3) + 8*(r>>2) + 4*hi5;
          const int pos = atomicAdd(&ccnt[rg], 1);
          if (pos < CAP) cand[(size_t)rg*CAP + pos] = j;
        }
      }
    }
  };

  // 1-deep software pipeline, even/odd B sets
  bf16x8 BhE[4], BlE[4], BhO[4], BlO[4];
  loadB(0, BhE, BlE);
  for (int c2 = 0; c2 < 16; ++c2) {
    loadB(2*c2+1, BhO, BlO);
    dochunk(2*c2, BhE, BlE);
    if (c2 < 15) loadB(2*c2+2, BhE, BlE);
    dochunk(2*c2+1, BhO, BlO);
  }

  if constexpr (MODE == 0) {
    const int row = t & 127, colh = t >> 7;
    const int part = q*2 + colh;
    const size_t rowg = bnn + i0 + row;
#pragma unroll
    for (int k = 0; k < KK; ++k) TV[(size_t)(part*KK + k)*BN + rowg] = tv[k];
  }
}

// ---------------- K2b: 20th-largest of 8x20 partials -> thr = t19 - margin
__global__ __launch_bounds__(256) void k2b_thr(
    const float* __restrict__ TV, float* __restrict__ thr) {
  const int rowg = blockIdx.x*256 + threadIdx.x;
  float tv[KK];
#pragma unroll
  for (int k = 0; k < KK; ++k) tv[k] = -INFINITY;
  for (int u = 0; u < 8*KK; ++u) NET_INS(TV[(size_t)u*BN + rowg])
  thr[rowg] = tv[KK-1] - MARGIN;
}

// ---------------- K2e: exact f32 dots on candidates, top-20 with numpy ties
__global__ __launch_bounds__(256) void k2e_exact(
    const float* __restrict__ XT, const float* __restrict__ xx,
    const int* __restrict__ ccnt, const int* __restrict__ cand,
    int* __restrict__ idxo) {
  const int t = threadIdx.x, w = t>>6, l = t&63;
  const int L = blockIdx.x;
  const int bbase = (L & 7) * NN;
  const int rowg = bbase + (L >> 3)*64 + w*16 + (l>>2);
  const int g = l & 3;
  const float* xip = XT + (size_t)rowg*64 + g*16;
  const float4 xi0 = *(const float4*)(xip),   xi1 = *(const float4*)(xip+4);
  const float4 xi2 = *(const float4*)(xip+8), xi3 = *(const float4*)(xip+12);
  const float xxi = xx[rowg];
  const int Cr = min(ccnt[rowg], CAP);
  int cmax = Cr;
#pragma unroll
  for (int off = 1; off < 64; off <<= 1) cmax = max(cmax, __shfl_xor(cmax, off));
  u64 kv[KK];
#pragma unroll
  for (int k = 0; k < KK; ++k) kv[k] = 0ULL;

  for (int c = 0; c < cmax; ++c) {
    const bool valid = (c < Cr);
    const int jj = valid ? cand[(size_t)rowg*CAP + c] : 0;
    const float* xjp = XT + ((size_t)(bbase + jj))*64 + g*16;
    const float4 a  = *(const float4*)(xjp),   b4 = *(const float4*)(xjp+4);
    const float4 c4 = *(const float4*)(xjp+8), d4 = *(const float4*)(xjp+12);
    float p = xi0.x*a.x;
    p = fmaf(xi0.y, a.y, p);  p = fmaf(xi0.z, a.z, p);  p = fmaf(xi0.w, a.w, p);
    p = fmaf(xi1.x, b4.x, p); p = fmaf(xi1.y, b4.y, p); p = fmaf(xi1.z, b4.z, p); p = fmaf(xi1.w, b4.w, p);
    p = fmaf(xi2.x, c4.x, p); p = fmaf(xi2.y, c4.y, p); p = fmaf(xi2.z, c4.z, p); p = fmaf(xi2.w, c4.w, p);
    p = fmaf(xi3.x, d4.x, p); p = fmaf(xi3.y, d4.y, p); p = fmaf(xi3.z, d4.z, p); p = fmaf(xi3.w, d4.w, p);
    p += __shfl_xor(p, 1);
    p += __shfl_xor(p, 2);
    const float d = 2.f*p - xxi - xx[bbase + jj];
    const u32 s = __float_as_uint(d);
    const u32 k32 = (s & 0x80000000u) ? ~s : (s | 0x80000000u);
    u64 key = ((u64)k32 << 32) | (u64)(0xFFFFFFFFu - (u32)jj);
    if (!valid) key = 0ULL;
#pragma unroll
    for (int qq = KK-1; qq >= 1; --qq) {
      const u64 mn = (kv[qq-1] < key) ? kv[qq-1] : key;
      if (kv[qq] < mn) kv[qq] = mn;
    }
    if (kv[0] < key) kv[0] = key;
  }
  if (g == 0) {
#pragma unroll
    for (int k = 0; k < KK; ++k)
      idxo[(size_t)rowg*KK + k] = (int)(0xFFFFFFFFu - (u32)(kv[k] & 0xFFFFFFFFu));
  }
}

// ---------------- K3: gather neighbors, per-(b,n,o) max/min of h, BN sums
__global__ __launch_bounds__(256) void k3_gather(
    const float* __restrict__ p1, const float* __restrict__ p2,
    const int* __restrict__ idx, float* __restrict__ maxh,
    float* __restrict__ minh, double* __restrict__ sums) {
  const int t = threadIdx.x;
  const int g = t >> 6, o = t & 63;
  const int L = blockIdx.x;
  const int bbase = (L & 7) * NN;
  const int pn0 = bbase + (L >> 3)*64 + g*16;
  float sacc = 0.f, ssacc = 0.f;

  for (int p = 0; p < 16; ++p) {
    const int pn = pn0 + p;
    const float p1v = p1[(size_t)pn*64 + o];
    const int* ip = idx + (size_t)pn*KK;
    float mx = -INFINITY, mn = INFINITY;
#pragma unroll
    for (int k = 0; k < KK; ++k) {
      const int j = ip[k];
      const float p2v = p2[((size_t)(bbase + j))*64 + o];
      const float h = p1v + p2v;
      mx = fmaxf(mx, h); mn = fminf(mn, h);
      sacc += h; ssacc += h*h;
    }
    maxh[(size_t)pn*64 + o] = mx;
    minh[(size_t)pn*64 + o] = mn;
  }

  __shared__ float rs[256], rss[256];
  rs[t] = sacc; rss[t] = ssacc;
  __syncthreads();
  if (t < 64) {
    const double sv  = (double)rs[t]  + (double)rs[t+64]  + (double)rs[t+128]  + (double)rs[t+192];
    const double ssv = (double)rss[t] + (double)rss[t+64] + (double)rss[t+128] + (double)rss[t+192];
    atomicAdd(&sums[t], sv);
    atomicAdd(&sums[64 + t], ssv);
  }
}

// ---------------- K4: finalize BN, activation, transpose to (b,o,n)
__global__ __launch_bounds__(256) void k4_out(
    const float* __restrict__ maxh, const float* __restrict__ minh,
    const double* __restrict__ sums, const float* __restrict__ gamma,
    const float* __restrict__ beta, float* __restrict__ out) {
  __shared__ float sc_[64], sh_[64];
  __shared__ float lmax[64*65], lmin[64*65];
  const int b  = blockIdx.y;
  const int n0 = blockIdx.x * 64;
  const int t  = threadIdx.x;

  if (t < 64) {
    const double mean = sums[t] / CNT_TOTAL;
    const double var  = sums[64 + t] / CNT_TOTAL - mean*mean;
    const float scale = gamma[t] * (float)(1.0 / sqrt(var + EPSV));
    sc_[t] = scale;
    sh_[t] = beta[t] - (float)mean * scale;
  }
#pragma unroll
  for (int r = 0; r < 16; ++r) {
    const int linear = r*256 + t;
    const int o = linear & 63, pos = linear >> 6;
    const size_t gg = ((size_t)(b*NN) + n0 + pos)*64 + o;
    lmax[o*65 + pos] = maxh[gg];
    lmin[o*65 + pos] = minh[gg];
  }
  __syncthreads();

  const int nn = t & 63;
  const int obase = (t >> 6) * 16;
#pragma unroll
  for (int r = 0; r < 16; ++r) {
    const int o = obase + r;
    const float scale = sc_[o], shift = sh_[o];
    const float src = (scale >= 0.f) ? lmax[o*65 + nn] : lmin[o*65 + nn];
    float v = scale*src + shift;
    v = (v >= 0.f) ? v : NEG_SLOPE*v;
    out[(size_t)b*CO*NN + (size_t)o*NN + n0 + nn] = v;
  }
}

extern "C" void kernel_launch(void* const* d_in, const int* in_sizes, int n_in,
                              void* d_out, int out_size, void* d_ws, size_t ws_size,
                              hipStream_t stream) {
  const float* x     = (const float*)d_in[0];
  const float* W     = (const float*)d_in[1];
  const float* gamma = (const float*)d_in[2];
  const float* beta  = (const float*)d_in[3];
  float* out = (float*)d_out;
  char* ws = (char*)d_ws;

  float*  p1   = (float*)(ws + OFF_P1);
  float*  p2   = (float*)(ws + OFF_P2);
  float*  xx   = (float*)(ws + OFF_XX);
  int*    idx  = (int*)  (ws + OFF_IDX);
  float*  XT   = (float*)(ws + OFF_XT);
  U16*    XH   = (U16*)  (ws + OFF_XH);
  U16*    XL   = (U16*)  (ws + OFF_XL);
  float*  TV   = (float*)(ws + OFF_TV);
  float*  thr  = (float*)(ws + OFF_THR);
  int*    cand = (int*)  (ws + OFF_CAND);
  int*    ccnt = (int*)  (ws + OFF_CCNT);
  float*  maxh = (float*)(ws + OFF_MAXH);
  float*  minh = (float*)(ws + OFF_MINH);
  double* sums = (double*)(ws + OFF_SUMS);

  // CCNT and SUMS are adjacent: one memset
  hipMemsetAsync(ws + OFF_CCNT, 0, (OFF_SUMS - OFF_CCNT) + 1024, stream);

  k0_repack <<<dim3(NN/64, BB), 256, 0, stream>>>(x, XT, XH, XL);
  k1_project<<<dim3(NN/64, BB), 256, 0, stream>>>(x, W, p1, p2, xx);
  k2ab<0>   <<<dim3(1024), 256, 0, stream>>>(XH, XL, xx, TV, thr, ccnt, cand);
  k2b_thr   <<<dim3(BN/256), 256, 0, stream>>>(TV, thr);
  k2ab<1>   <<<dim3(1024), 256, 0, stream>>>(XH, XL, xx, TV, thr, ccnt, cand);
  k2e_exact <<<dim3(BN/64), 256, 0, stream>>>(XT, xx, ccnt, cand, idx);
  k3_gather <<<dim3(BN/64), 256, 0, stream>>>(p1, p2, idx, maxh, minh, sums);
  k4_out    <<<dim3(NN/64, BB), 256, 0, stream>>>(maxh, minh, sums, gamma, beta, out);
}

// Round 8
// 468.551 us; speedup vs baseline: 1.6133x; 1.4762x over previous
//
#include <hip/hip_runtime.h>
#include <hip/hip_bf16.h>
#include <math.h>

// Problem constants
#define BB 8
#define CC 64
#define NN 4096
#define CO 64
#define KK 20
#define BN (BB*NN)           // 32768 rows
#define CN (CC*NN)           // 262144
#define EPSV 1e-5
#define NEG_SLOPE 0.2f
#define CNT_TOTAL 655360.0   // B*N*K
#define CAP 64
#define MARGIN 0.75f

typedef unsigned short U16;
typedef unsigned int u32;
typedef unsigned long long u64;
typedef __attribute__((ext_vector_type(8))) __bf16 bf16x8;
typedef __attribute__((ext_vector_type(16))) float f32x16;

// Workspace layout (bytes). MAXH/MINH alias TV (TV dead after k2b).
#define OFF_P1    ((size_t)0)
#define OFF_P2    ((size_t)8388608)
#define OFF_XX    ((size_t)16777216)
#define OFF_IDX   ((size_t)16908288)
#define OFF_XT    ((size_t)19529728)
#define OFF_XB    ((size_t)27918336)   // BN*64 bf16
#define OFF_TV    ((size_t)36306944)   // BN*8*20 f32 = 20971520
#define OFF_THR   ((size_t)57278464)
#define OFF_CAND  ((size_t)57409536)   // BN*CAP i32
#define OFF_CCNT  ((size_t)65798144)   // zeroed
#define OFF_SUMS  ((size_t)65929216)   // zeroed (adjacent to CCNT)
#define OFF_MAXH  ((size_t)36306944)   // alias TV
#define OFF_MINH  ((size_t)44695552)

// sorted-desc insert; invariant tv[q-1]>=tv[q] -> max(min(hi,d),lo) == med3
#define NET_INS(dv) { const float d_ = (dv); _Pragma("unroll") \
  for (int q_ = KK-1; q_ >= 1; --q_) tv[q_] = __builtin_amdgcn_fmed3f(tv[q_-1], d_, tv[q_]); \
  tv[0] = fmaxf(tv[0], d_); }

// ---------------- K0: transpose x -> XT f32 [B][N][64], XB bf16
__global__ __launch_bounds__(256) void k0_repack(
    const float* __restrict__ x, float* __restrict__ XT,
    U16* __restrict__ XB) {
  __shared__ float tile[64*65];
  const int b = blockIdx.y, n0 = blockIdx.x*64, t = threadIdx.x;
#pragma unroll
  for (int r = 0; r < 16; ++r) {
    const int c = r*4 + (t>>6);
    const int nn = t & 63;
    tile[c*65 + nn] = x[(size_t)b*CN + (size_t)c*NN + n0 + nn];
  }
  __syncthreads();
  const int g = t>>6, pos = t&63;
  float v[16];
#pragma unroll
  for (int cc = 0; cc < 16; ++cc) v[cc] = tile[(g*16+cc)*65 + pos];
  const size_t base = ((size_t)(b*NN + n0 + pos))*64 + g*16;
#pragma unroll
  for (int u = 0; u < 4; ++u)
    *(float4*)(XT + base + u*4) = make_float4(v[u*4],v[u*4+1],v[u*4+2],v[u*4+3]);
  U16 hb[16];
#pragma unroll
  for (int cc = 0; cc < 16; ++cc) {
    __hip_bfloat16 h = __float2bfloat16(v[cc]);
    hb[cc] = reinterpret_cast<U16&>(h);
  }
  uint hw[8];
#pragma unroll
  for (int u = 0; u < 8; ++u) hw[u] = (uint)hb[2*u] | ((uint)hb[2*u+1] << 16);
  *(uint4*)(XB + base)     = make_uint4(hw[0],hw[1],hw[2],hw[3]);
  *(uint4*)(XB + base + 8) = make_uint4(hw[4],hw[5],hw[6],hw[7]);
}

// ---------------- K1: projections p1=(W1-W2)x, p2=W2 x, xx=|x|^2
__global__ __launch_bounds__(256) void k1_project(
    const float* __restrict__ x, const float* __restrict__ W,
    float* __restrict__ p1, float* __restrict__ p2, float* __restrict__ xx) {
  const int b  = blockIdx.y;
  const int n0 = blockIdx.x * 64;
  const int t  = threadIdx.x;
  const int pos = t & 63, og = t >> 6;
  const int n = n0 + pos;
  const float* xb = x + (size_t)b*CN + n;

  float a1[16], a2[16];
#pragma unroll
  for (int i = 0; i < 16; ++i) { a1[i] = 0.f; a2[i] = 0.f; }
  float xxa = 0.f;
#pragma unroll
  for (int c4 = 0; c4 < 16; ++c4) {
    float xv[4];
#pragma unroll
    for (int u = 0; u < 4; ++u) xv[u] = xb[(size_t)(c4*4+u)*NN];
    if (og == 0) xxa += xv[0]*xv[0] + xv[1]*xv[1] + xv[2]*xv[2] + xv[3]*xv[3];
#pragma unroll
    for (int oi = 0; oi < 16; ++oi) {
      const int o = og*16 + oi;
      const float4 w1 = *(const float4*)(W + o*128 + c4*4);
      const float4 w2 = *(const float4*)(W + o*128 + 64 + c4*4);
      a1[oi] += (w1.x - w2.x)*xv[0] + (w1.y - w2.y)*xv[1]
              + (w1.z - w2.z)*xv[2] + (w1.w - w2.w)*xv[3];
      a2[oi] += w2.x*xv[0] + w2.y*xv[1] + w2.z*xv[2] + w2.w*xv[3];
    }
  }
  float* p1o = p1 + ((size_t)(b*NN + n))*64 + og*16;
  float* p2o = p2 + ((size_t)(b*NN + n))*64 + og*16;
#pragma unroll
  for (int oi = 0; oi < 16; ++oi) { p1o[oi] = a1[oi]; p2o[oi] = a2[oi]; }
  if (og == 0) xx[b*NN + n] = xxa;
}

// ---------------- K2ab: swapped-operand MFMA Gram, scan in-register.
// D[row=j][col=i]: lane owns query i = lo5; 16 j-candidates per chunk in acc.
// 1D grid 1024: b = L&7 (XCD pin), q = (L>>3)&3, bx = L>>5.
#define LOADA(ch, A0_,A1_,A2_,A3_) { \
  const U16* ap_ = XB + (bnn + jbase + (size_t)(ch)*32 + lo5)*64 + ch0; \
  A0_ = *(const bf16x8*)(ap_);      A1_ = *(const bf16x8*)(ap_+16); \
  A2_ = *(const bf16x8*)(ap_+32);   A3_ = *(const bf16x8*)(ap_+48); }

#define DOCHUNK(ch, A0_,A1_,A2_,A3_) { \
  f32x16 acc_; \
  _Pragma("unroll") for (int r_ = 0; r_ < 16; ++r_) acc_[r_] = 0.f; \
  acc_ = __builtin_amdgcn_mfma_f32_32x32x16_bf16(A0_, Bi0, acc_, 0,0,0); \
  acc_ = __builtin_amdgcn_mfma_f32_32x32x16_bf16(A1_, Bi1, acc_, 0,0,0); \
  acc_ = __builtin_amdgcn_mfma_f32_32x32x16_bf16(A2_, Bi2, acc_, 0,0,0); \
  acc_ = __builtin_amdgcn_mfma_f32_32x32x16_bf16(A3_, Bi3, acc_, 0,0,0); \
  const float* xp_ = xxs + (ch)*32 + 4*hi5; \
  const float4 x0_ = *(const float4*)(xp_); \
  const float4 x1_ = *(const float4*)(xp_ + 8); \
  const float4 x2_ = *(const float4*)(xp_ + 16); \
  const float4 x3_ = *(const float4*)(xp_ + 24); \
  float xa_[16]; \
  xa_[0]=x0_.x; xa_[1]=x0_.y; xa_[2]=x0_.z; xa_[3]=x0_.w; \
  xa_[4]=x1_.x; xa_[5]=x1_.y; xa_[6]=x1_.z; xa_[7]=x1_.w; \
  xa_[8]=x2_.x; xa_[9]=x2_.y; xa_[10]=x2_.z; xa_[11]=x2_.w; \
  xa_[12]=x3_.x; xa_[13]=x3_.y; xa_[14]=x3_.z; xa_[15]=x3_.w; \
  if constexpr (MODE == 0) { \
    _Pragma("unroll") for (int r_ = 0; r_ < 16; ++r_) \
      NET_INS(fmaf(2.f, acc_[r_], -xa_[r_])) \
  } else { \
    const int jb_ = jbase + (ch)*32 + 4*hi5; \
    _Pragma("unroll") for (int r_ = 0; r_ < 16; ++r_) { \
      const float dd_ = fmaf(2.f, acc_[r_], -xa_[r_]); \
      if (dd_ >= thrv) { \
        const int pos_ = atomicAdd(&ccnt[rowg], 1); \
        if (pos_ < CAP) cand[rowg*CAP + pos_] = jb_ + (r_&3) + 8*(r_>>2); \
      } \
    } \
  } }

template<int MODE>
__global__ __launch_bounds__(256, 4) void k2ab(
    const U16* __restrict__ XB, const float* __restrict__ xx,
    float* __restrict__ TV, const float* __restrict__ thr,
    int* __restrict__ ccnt, int* __restrict__ cand) {
  __shared__ float xxs[1024];
  const int L = blockIdx.x;
  const int b = L & 7, q = (L >> 3) & 3, bx = L >> 5;
  const int i0 = bx * 128;
  const int t = threadIdx.x, w = t>>6, l = t&63, lo5 = l&31, hi5 = l>>5;
  const int ch0 = 8*hi5;
  const size_t bnn = (size_t)b*NN;
  const int jbase = q*1024;
  const size_t rowg = bnn + i0 + w*32 + lo5;   // this lane's query row

  *(float4*)(xxs + t*4) = *(const float4*)(xx + bnn + jbase + t*4);
  __syncthreads();

  // B-operand: own query row, 4 k-slices (static for whole kernel)
  const U16* bp = XB + rowg*64 + ch0;
  const bf16x8 Bi0 = *(const bf16x8*)(bp);
  const bf16x8 Bi1 = *(const bf16x8*)(bp + 16);
  const bf16x8 Bi2 = *(const bf16x8*)(bp + 32);
  const bf16x8 Bi3 = *(const bf16x8*)(bp + 48);

  float tv[KK];
  float thrv = 0.f;
  if constexpr (MODE == 0) {
#pragma unroll
    for (int k = 0; k < KK; ++k) tv[k] = -INFINITY;
  } else {
    thrv = thr[rowg];
  }

  bf16x8 AE0,AE1,AE2,AE3, AO0,AO1,AO2,AO3;
  LOADA(0, AE0,AE1,AE2,AE3)
  for (int c2 = 0; c2 < 16; ++c2) {
    LOADA(2*c2+1, AO0,AO1,AO2,AO3)
    DOCHUNK(2*c2, AE0,AE1,AE2,AE3)
    if (c2 < 15) LOADA(2*c2+2, AE0,AE1,AE2,AE3)
    DOCHUNK(2*c2+1, AO0,AO1,AO2,AO3)
  }

  if constexpr (MODE == 0) {
    const int part = q*2 + hi5;
#pragma unroll
    for (int k = 0; k < KK; ++k) TV[(size_t)(part*KK + k)*BN + rowg] = tv[k];
  }
}

// ---------------- K2b: 20th-largest of 8x20 partials -> thr = t19 - margin
__global__ __launch_bounds__(256) void k2b_thr(
    const float* __restrict__ TV, float* __restrict__ thr) {
  const int rowg = blockIdx.x*256 + threadIdx.x;
  float tv[KK];
#pragma unroll
  for (int k = 0; k < KK; ++k) tv[k] = -INFINITY;
  for (int u = 0; u < 8*KK; ++u) NET_INS(TV[(size_t)u*BN + rowg])
  thr[rowg] = tv[KK-1] - MARGIN;
}

// ---------------- K2e: exact f32 dots on candidates, top-20 with numpy ties
__global__ __launch_bounds__(256) void k2e_exact(
    const float* __restrict__ XT, const float* __restrict__ xx,
    const int* __restrict__ ccnt, const int* __restrict__ cand,
    int* __restrict__ idxo) {
  const int t = threadIdx.x, w = t>>6, l = t&63;
  const int L = blockIdx.x;
  const int bbase = (L & 7) * NN;
  const int rowg = bbase + (L >> 3)*64 + w*16 + (l>>2);
  const int g = l & 3;
  const float* xip = XT + (size_t)rowg*64 + g*16;
  const float4 xi0 = *(const float4*)(xip),   xi1 = *(const float4*)(xip+4);
  const float4 xi2 = *(const float4*)(xip+8), xi3 = *(const float4*)(xip+12);
  const float xxi = xx[rowg];
  const int Cr = min(ccnt[rowg], CAP);
  int cmax = Cr;
#pragma unroll
  for (int off = 1; off < 64; off <<= 1) cmax = max(cmax, __shfl_xor(cmax, off));
  u64 kv[KK];
#pragma unroll
  for (int k = 0; k < KK; ++k) kv[k] = 0ULL;

  for (int c = 0; c < cmax; ++c) {
    const bool valid = (c < Cr);
    const int jj = valid ? cand[(size_t)rowg*CAP + c] : 0;
    const float* xjp = XT + ((size_t)(bbase + jj))*64 + g*16;
    const float4 a  = *(const float4*)(xjp),   b4 = *(const float4*)(xjp+4);
    const float4 c4 = *(const float4*)(xjp+8), d4 = *(const float4*)(xjp+12);
    float p = xi0.x*a.x;
    p = fmaf(xi0.y, a.y, p);  p = fmaf(xi0.z, a.z, p);  p = fmaf(xi0.w, a.w, p);
    p = fmaf(xi1.x, b4.x, p); p = fmaf(xi1.y, b4.y, p); p = fmaf(xi1.z, b4.z, p); p = fmaf(xi1.w, b4.w, p);
    p = fmaf(xi2.x, c4.x, p); p = fmaf(xi2.y, c4.y, p); p = fmaf(xi2.z, c4.z, p); p = fmaf(xi2.w, c4.w, p);
    p = fmaf(xi3.x, d4.x, p); p = fmaf(xi3.y, d4.y, p); p = fmaf(xi3.z, d4.z, p); p = fmaf(xi3.w, d4.w, p);
    p += __shfl_xor(p, 1);
    p += __shfl_xor(p, 2);
    const float d = 2.f*p - xxi - xx[bbase + jj];
    const u32 s = __float_as_uint(d);
    const u32 k32 = (s & 0x80000000u) ? ~s : (s | 0x80000000u);
    u64 key = ((u64)k32 << 32) | (u64)(0xFFFFFFFFu - (u32)jj);
    if (!valid) key = 0ULL;
#pragma unroll
    for (int qq = KK-1; qq >= 1; --qq) {
      const u64 mn = (kv[qq-1] < key) ? kv[qq-1] : key;
      if (kv[qq] < mn) kv[qq] = mn;
    }
    if (kv[0] < key) kv[0] = key;
  }
  if (g == 0) {
#pragma unroll
    for (int k = 0; k < KK; ++k)
      idxo[(size_t)rowg*KK + k] = (int)(0xFFFFFFFFu - (u32)(kv[k] & 0xFFFFFFFFu));
  }
}

// ---------------- K3: gather neighbors, per-(b,n,o) max/min of h, BN sums
__global__ __launch_bounds__(256) void k3_gather(
    const float* __restrict__ p1, const float* __restrict__ p2,
    const int* __restrict__ idx, float* __restrict__ maxh,
    float* __restrict__ minh, double* __restrict__ sums) {
  const int t = threadIdx.x;
  const int g = t >> 6, o = t & 63;
  const int L = blockIdx.x;
  const int bbase = (L & 7) * NN;
  const int pn0 = bbase + (L >> 3)*64 + g*16;
  float sacc = 0.f, ssacc = 0.f;

  for (int p = 0; p < 16; ++p) {
    const int pn = pn0 + p;
    const float p1v = p1[(size_t)pn*64 + o];
    const int* ip = idx + (size_t)pn*KK;
    float mx = -INFINITY, mn = INFINITY;
#pragma unroll
    for (int k = 0; k < KK; ++k) {
      const int j = ip[k];
      const float p2v = p2[((size_t)(bbase + j))*64 + o];
      const float h = p1v + p2v;
      mx = fmaxf(mx, h); mn = fminf(mn, h);
      sacc += h; ssacc += h*h;
    }
    maxh[(size_t)pn*64 + o] = mx;
    minh[(size_t)pn*64 + o] = mn;
  }

  __shared__ float rs[256], rss[256];
  rs[t] = sacc; rss[t] = ssacc;
  __syncthreads();
  if (t < 64) {
    const double sv  = (double)rs[t]  + (double)rs[t+64]  + (double)rs[t+128]  + (double)rs[t+192];
    const double ssv = (double)rss[t] + (double)rss[t+64] + (double)rss[t+128] + (double)rss[t+192];
    atomicAdd(&sums[t], sv);
    atomicAdd(&sums[64 + t], ssv);
  }
}

// ---------------- K4: finalize BN, activation, transpose to (b,o,n)
__global__ __launch_bounds__(256) void k4_out(
    const float* __restrict__ maxh, const float* __restrict__ minh,
    const double* __restrict__ sums, const float* __restrict__ gamma,
    const float* __restrict__ beta, float* __restrict__ out) {
  __shared__ float sc_[64], sh_[64];
  __shared__ float lmax[64*65], lmin[64*65];
  const int b  = blockIdx.y;
  const int n0 = blockIdx.x * 64;
  const int t  = threadIdx.x;

  if (t < 64) {
    const double mean = sums[t] / CNT_TOTAL;
    const double var  = sums[64 + t] / CNT_TOTAL - mean*mean;
    const float scale = gamma[t] * (float)(1.0 / sqrt(var + EPSV));
    sc_[t] = scale;
    sh_[t] = beta[t] - (float)mean * scale;
  }
#pragma unroll
  for (int r = 0; r < 16; ++r) {
    const int linear = r*256 + t;
    const int o = linear & 63, pos = linear >> 6;
    const size_t gg = ((size_t)(b*NN) + n0 + pos)*64 + o;
    lmax[o*65 + pos] = maxh[gg];
    lmin[o*65 + pos] = minh[gg];
  }
  __syncthreads();

  const int nn = t & 63;
  const int obase = (t >> 6) * 16;
#pragma unroll
  for (int r = 0; r < 16; ++r) {
    const int o = obase + r;
    const float scale = sc_[o], shift = sh_[o];
    const float src = (scale >= 0.f) ? lmax[o*65 + nn] : lmin[o*65 + nn];
    float v = scale*src + shift;
    v = (v >= 0.f) ? v : NEG_SLOPE*v;
    out[(size_t)b*CO*NN + (size_t)o*NN + n0 + nn] = v;
  }
}

extern "C" void kernel_launch(void* const* d_in, const int* in_sizes, int n_in,
                              void* d_out, int out_size, void* d_ws, size_t ws_size,
                              hipStream_t stream) {
  const float* x     = (const float*)d_in[0];
  const float* W     = (const float*)d_in[1];
  const float* gamma = (const float*)d_in[2];
  const float* beta  = (const float*)d_in[3];
  float* out = (float*)d_out;
  char* ws = (char*)d_ws;

  float*  p1   = (float*)(ws + OFF_P1);
  float*  p2   = (float*)(ws + OFF_P2);
  float*  xx   = (float*)(ws + OFF_XX);
  int*    idx  = (int*)  (ws + OFF_IDX);
  float*  XT   = (float*)(ws + OFF_XT);
  U16*    XB   = (U16*)  (ws + OFF_XB);
  float*  TV   = (float*)(ws + OFF_TV);
  float*  thr  = (float*)(ws + OFF_THR);
  int*    cand = (int*)  (ws + OFF_CAND);
  int*    ccnt = (int*)  (ws + OFF_CCNT);
  float*  maxh = (float*)(ws + OFF_MAXH);
  float*  minh = (float*)(ws + OFF_MINH);
  double* sums = (double*)(ws + OFF_SUMS);

  // CCNT and SUMS are adjacent: one memset
  hipMemsetAsync(ws + OFF_CCNT, 0, (OFF_SUMS - OFF_CCNT) + 1024, stream);

  k0_repack <<<dim3(NN/64, BB), 256, 0, stream>>>(x, XT, XB);
  k1_project<<<dim3(NN/64, BB), 256, 0, stream>>>(x, W, p1, p2, xx);
  k2ab<0>   <<<dim3(1024), 256, 0, stream>>>(XB, xx, TV, thr, ccnt, cand);
  k2b_thr   <<<dim3(BN/256), 256, 0, stream>>>(TV, thr);
  k2ab<1>   <<<dim3(1024), 256, 0, stream>>>(XB, xx, TV, thr, ccnt, cand);
  k2e_exact <<<dim3(BN/64), 256, 0, stream>>>(XT, xx, ccnt, cand, idx);
  k3_gather <<<dim3(BN/64), 256, 0, stream>>>(p1, p2, idx, maxh, minh, sums);
  k4_out    <<<dim3(NN/64, BB), 256, 0, stream>>>(maxh, minh, sums, gamma, beta, out);
}

// Round 9
// 355.030 us; speedup vs baseline: 2.1291x; 1.3198x over previous
//
#include <hip/hip_runtime.h>
#include <hip/hip_bf16.h>
#include <math.h>

// Problem constants
#define BB 8
#define CC 64
#define NN 4096
#define CO 64
#define KK 20
#define BN (BB*NN)           // 32768 rows
#define CN (CC*NN)           // 262144
#define EPSV 1e-5
#define NEG_SLOPE 0.2f
#define CNT_TOTAL 655360.0   // B*N*K
#define CAP 64
#define MARGIN 0.75f

typedef unsigned short U16;
typedef unsigned int u32;
typedef unsigned long long u64;
typedef __attribute__((ext_vector_type(8))) __bf16 bf16x8;
typedef __attribute__((ext_vector_type(16))) float f32x16;

// Workspace layout (bytes). MAXH/MINH alias TV (TV dead after k2b).
#define OFF_P1    ((size_t)0)
#define OFF_P2    ((size_t)8388608)
#define OFF_XX    ((size_t)16777216)
#define OFF_IDX   ((size_t)16908288)
#define OFF_XT    ((size_t)19529728)
#define OFF_XB    ((size_t)27918336)   // BN*64 bf16
#define OFF_TV    ((size_t)36306944)   // BN*8*20 f32 = 20971520
#define OFF_THR   ((size_t)57278464)
#define OFF_CAND  ((size_t)57409536)   // BN*CAP i32
#define OFF_CCNT  ((size_t)65798144)   // zeroed
#define OFF_SUMS  ((size_t)65929216)   // zeroed (adjacent to CCNT)
#define OFF_MAXH  ((size_t)36306944)   // alias TV
#define OFF_MINH  ((size_t)44695552)

// sorted-desc insert; invariant tv[q-1]>=tv[q] -> max(min(hi,d),lo) == med3
#define NET_INS(dv) { const float d_ = (dv); _Pragma("unroll") \
  for (int q_ = KK-1; q_ >= 1; --q_) tv[q_] = __builtin_amdgcn_fmed3f(tv[q_-1], d_, tv[q_]); \
  tv[0] = fmaxf(tv[0], d_); }

// ---------------- K0: transpose x -> XT f32 [B][N][64], XB bf16
__global__ __launch_bounds__(256) void k0_repack(
    const float* __restrict__ x, float* __restrict__ XT,
    U16* __restrict__ XB) {
  __shared__ float tile[64*65];
  const int b = blockIdx.y, n0 = blockIdx.x*64, t = threadIdx.x;
#pragma unroll
  for (int r = 0; r < 16; ++r) {
    const int c = r*4 + (t>>6);
    const int nn = t & 63;
    tile[c*65 + nn] = x[(size_t)b*CN + (size_t)c*NN + n0 + nn];
  }
  __syncthreads();
  const int g = t>>6, pos = t&63;
  float v[16];
#pragma unroll
  for (int cc = 0; cc < 16; ++cc) v[cc] = tile[(g*16+cc)*65 + pos];
  const size_t base = ((size_t)(b*NN + n0 + pos))*64 + g*16;
#pragma unroll
  for (int u = 0; u < 4; ++u)
    *(float4*)(XT + base + u*4) = make_float4(v[u*4],v[u*4+1],v[u*4+2],v[u*4+3]);
  U16 hb[16];
#pragma unroll
  for (int cc = 0; cc < 16; ++cc) {
    __hip_bfloat16 h = __float2bfloat16(v[cc]);
    hb[cc] = reinterpret_cast<U16&>(h);
  }
  uint hw[8];
#pragma unroll
  for (int u = 0; u < 8; ++u) hw[u] = (uint)hb[2*u] | ((uint)hb[2*u+1] << 16);
  *(uint4*)(XB + base)     = make_uint4(hw[0],hw[1],hw[2],hw[3]);
  *(uint4*)(XB + base + 8) = make_uint4(hw[4],hw[5],hw[6],hw[7]);
}

// ---------------- K1: LDS-tiled f32 GEMM: [p1;p2] = [[W1-W2];[W2]] * x, + xx
// Block: 64 points x 128 outputs. Thread: 4 outputs x 8 points (acc[4][8]).
__global__ __launch_bounds__(256) void k1_project(
    const float* __restrict__ x, const float* __restrict__ W,
    float* __restrict__ p1, float* __restrict__ p2, float* __restrict__ xx) {
  __shared__ float Wt[64*128];   // [c][o]: o<64 -> W1-W2, o>=64 -> W2   (32 KB)
  __shared__ float xt[64*64];    // [c][pt]                              (16 KB)
  const int b  = blockIdx.y;
  const int n0 = blockIdx.x * 64;
  const int t  = threadIdx.x;

#pragma unroll
  for (int r = 0; r < 16; ++r) {     // 4096 = 64c x 64o
    const int lin = r*256 + t;
    const int c = lin >> 6, o = lin & 63;
    const float w1 = W[o*128 + c];
    const float w2 = W[o*128 + 64 + c];
    Wt[c*128 + o]      = w1 - w2;
    Wt[c*128 + 64 + o] = w2;
  }
#pragma unroll
  for (int r = 0; r < 16; ++r) {     // 4096 = 64c x 64pt
    const int lin = r*256 + t;
    const int c = lin >> 6, pt = lin & 63;
    xt[c*64 + pt] = x[((size_t)b*64 + c)*NN + n0 + pt];
  }
  __syncthreads();

  const int o0  = (t & 31) * 4;      // 0..124
  const int pt0 = (t >> 5) * 8;      // 0..56
  float acc[4][8];
#pragma unroll
  for (int i = 0; i < 4; ++i)
#pragma unroll
    for (int j = 0; j < 8; ++j) acc[i][j] = 0.f;

  for (int c = 0; c < 64; ++c) {
    const float4 w4 = *(const float4*)(Wt + c*128 + o0);
    const float4 xa = *(const float4*)(xt + c*64 + pt0);
    const float4 xb = *(const float4*)(xt + c*64 + pt0 + 4);
    float wv[4] = {w4.x, w4.y, w4.z, w4.w};
    float xv[8] = {xa.x, xa.y, xa.z, xa.w, xb.x, xb.y, xb.z, xb.w};
#pragma unroll
    for (int i = 0; i < 4; ++i)
#pragma unroll
      for (int j = 0; j < 8; ++j) acc[i][j] = fmaf(wv[i], xv[j], acc[i][j]);
  }

  float* basep = (o0 < 64) ? (p1 + o0) : (p2 + o0 - 64);
#pragma unroll
  for (int j = 0; j < 8; ++j) {
    const size_t pn = (size_t)b*NN + n0 + pt0 + j;
    *(float4*)(basep + pn*64) = make_float4(acc[0][j], acc[1][j], acc[2][j], acc[3][j]);
  }

  if (t < 64) {
    float s = 0.f;
    for (int c = 0; c < 64; ++c) s = fmaf(xt[c*64 + t], xt[c*64 + t], s);
    xx[b*NN + n0 + t] = s;
  }
}

// ---------------- K2ab: swapped-operand MFMA Gram, scan in-register.
// D[row=j][col=i]: lane owns query i = lo5; 16 j-candidates per chunk in acc.
// 1D grid 1024: b = L&7 (XCD pin), q = (L>>3)&3, bx = L>>5.
#define LOADA(ch, A0_,A1_,A2_,A3_) { \
  const U16* ap_ = XB + (bnn + jbase + (size_t)(ch)*32 + lo5)*64 + ch0; \
  A0_ = *(const bf16x8*)(ap_);      A1_ = *(const bf16x8*)(ap_+16); \
  A2_ = *(const bf16x8*)(ap_+32);   A3_ = *(const bf16x8*)(ap_+48); }

#define DOCHUNK(ch, A0_,A1_,A2_,A3_) { \
  f32x16 acc_; \
  _Pragma("unroll") for (int r_ = 0; r_ < 16; ++r_) acc_[r_] = 0.f; \
  acc_ = __builtin_amdgcn_mfma_f32_32x32x16_bf16(A0_, Bi0, acc_, 0,0,0); \
  acc_ = __builtin_amdgcn_mfma_f32_32x32x16_bf16(A1_, Bi1, acc_, 0,0,0); \
  acc_ = __builtin_amdgcn_mfma_f32_32x32x16_bf16(A2_, Bi2, acc_, 0,0,0); \
  acc_ = __builtin_amdgcn_mfma_f32_32x32x16_bf16(A3_, Bi3, acc_, 0,0,0); \
  const float* xp_ = xxs + (ch)*32 + 4*hi5; \
  const float4 x0_ = *(const float4*)(xp_); \
  const float4 x1_ = *(const float4*)(xp_ + 8); \
  const float4 x2_ = *(const float4*)(xp_ + 16); \
  const float4 x3_ = *(const float4*)(xp_ + 24); \
  float xa_[16]; \
  xa_[0]=x0_.x; xa_[1]=x0_.y; xa_[2]=x0_.z; xa_[3]=x0_.w; \
  xa_[4]=x1_.x; xa_[5]=x1_.y; xa_[6]=x1_.z; xa_[7]=x1_.w; \
  xa_[8]=x2_.x; xa_[9]=x2_.y; xa_[10]=x2_.z; xa_[11]=x2_.w; \
  xa_[12]=x3_.x; xa_[13]=x3_.y; xa_[14]=x3_.z; xa_[15]=x3_.w; \
  if constexpr (MODE == 0) { \
    _Pragma("unroll") for (int r_ = 0; r_ < 16; ++r_) \
      NET_INS(fmaf(2.f, acc_[r_], -xa_[r_])) \
  } else { \
    const int jb_ = jbase + (ch)*32 + 4*hi5; \
    _Pragma("unroll") for (int r_ = 0; r_ < 16; ++r_) { \
      const float dd_ = fmaf(2.f, acc_[r_], -xa_[r_]); \
      if (dd_ >= thrv) { \
        const int pos_ = atomicAdd(&ccnt[rowg], 1); \
        if (pos_ < CAP) cand[rowg*CAP + pos_] = jb_ + (r_&3) + 8*(r_>>2); \
      } \
    } \
  } }

template<int MODE>
__global__ __launch_bounds__(256, 4) void k2ab(
    const U16* __restrict__ XB, const float* __restrict__ xx,
    float* __restrict__ TV, const float* __restrict__ thr,
    int* __restrict__ ccnt, int* __restrict__ cand) {
  __shared__ float xxs[1024];
  const int L = blockIdx.x;
  const int b = L & 7, q = (L >> 3) & 3, bx = L >> 5;
  const int i0 = bx * 128;
  const int t = threadIdx.x, w = t>>6, l = t&63, lo5 = l&31, hi5 = l>>5;
  const int ch0 = 8*hi5;
  const size_t bnn = (size_t)b*NN;
  const int jbase = q*1024;
  const size_t rowg = bnn + i0 + w*32 + lo5;   // this lane's query row

  *(float4*)(xxs + t*4) = *(const float4*)(xx + bnn + jbase + t*4);
  __syncthreads();

  // B-operand: own query row, 4 k-slices (static for whole kernel)
  const U16* bp = XB + rowg*64 + ch0;
  const bf16x8 Bi0 = *(const bf16x8*)(bp);
  const bf16x8 Bi1 = *(const bf16x8*)(bp + 16);
  const bf16x8 Bi2 = *(const bf16x8*)(bp + 32);
  const bf16x8 Bi3 = *(const bf16x8*)(bp + 48);

  float tv[KK];
  float thrv = 0.f;
  if constexpr (MODE == 0) {
#pragma unroll
    for (int k = 0; k < KK; ++k) tv[k] = -INFINITY;
  } else {
    thrv = thr[rowg];
  }

  bf16x8 AE0,AE1,AE2,AE3, AO0,AO1,AO2,AO3;
  LOADA(0, AE0,AE1,AE2,AE3)
  for (int c2 = 0; c2 < 16; ++c2) {
    LOADA(2*c2+1, AO0,AO1,AO2,AO3)
    DOCHUNK(2*c2, AE0,AE1,AE2,AE3)
    if (c2 < 15) LOADA(2*c2+2, AE0,AE1,AE2,AE3)
    DOCHUNK(2*c2+1, AO0,AO1,AO2,AO3)
  }

  if constexpr (MODE == 0) {
    const int part = q*2 + hi5;
#pragma unroll
    for (int k = 0; k < KK; ++k) TV[(size_t)(part*KK + k)*BN + rowg] = tv[k];
  }
}

// ---------------- K2b: 20th-largest of 8x20 partials -> thr = t19 - margin
__global__ __launch_bounds__(256) void k2b_thr(
    const float* __restrict__ TV, float* __restrict__ thr) {
  const int rowg = blockIdx.x*256 + threadIdx.x;
  float tv[KK];
#pragma unroll
  for (int k = 0; k < KK; ++k) tv[k] = -INFINITY;
  for (int u = 0; u < 8*KK; ++u) NET_INS(TV[(size_t)u*BN + rowg])
  thr[rowg] = tv[KK-1] - MARGIN;
}

// ---------------- K2e: exact f32 dots on candidates, top-20 with numpy ties
__global__ __launch_bounds__(256) void k2e_exact(
    const float* __restrict__ XT, const float* __restrict__ xx,
    const int* __restrict__ ccnt, const int* __restrict__ cand,
    int* __restrict__ idxo) {
  const int t = threadIdx.x, w = t>>6, l = t&63;
  const int L = blockIdx.x;
  const int bbase = (L & 7) * NN;
  const int rowg = bbase + (L >> 3)*64 + w*16 + (l>>2);
  const int g = l & 3;
  const float* xip = XT + (size_t)rowg*64 + g*16;
  const float4 xi0 = *(const float4*)(xip),   xi1 = *(const float4*)(xip+4);
  const float4 xi2 = *(const float4*)(xip+8), xi3 = *(const float4*)(xip+12);
  const float xxi = xx[rowg];
  const int Cr = min(ccnt[rowg], CAP);
  int cmax = Cr;
#pragma unroll
  for (int off = 1; off < 64; off <<= 1) cmax = max(cmax, __shfl_xor(cmax, off));
  u64 kv[KK];
#pragma unroll
  for (int k = 0; k < KK; ++k) kv[k] = 0ULL;

  for (int c = 0; c < cmax; ++c) {
    const bool valid = (c < Cr);
    const int jj = valid ? cand[(size_t)rowg*CAP + c] : 0;
    const float* xjp = XT + ((size_t)(bbase + jj))*64 + g*16;
    const float4 a  = *(const float4*)(xjp),   b4 = *(const float4*)(xjp+4);
    const float4 c4 = *(const float4*)(xjp+8), d4 = *(const float4*)(xjp+12);
    float p = xi0.x*a.x;
    p = fmaf(xi0.y, a.y, p);  p = fmaf(xi0.z, a.z, p);  p = fmaf(xi0.w, a.w, p);
    p = fmaf(xi1.x, b4.x, p); p = fmaf(xi1.y, b4.y, p); p = fmaf(xi1.z, b4.z, p); p = fmaf(xi1.w, b4.w, p);
    p = fmaf(xi2.x, c4.x, p); p = fmaf(xi2.y, c4.y, p); p = fmaf(xi2.z, c4.z, p); p = fmaf(xi2.w, c4.w, p);
    p = fmaf(xi3.x, d4.x, p); p = fmaf(xi3.y, d4.y, p); p = fmaf(xi3.z, d4.z, p); p = fmaf(xi3.w, d4.w, p);
    p += __shfl_xor(p, 1);
    p += __shfl_xor(p, 2);
    const float d = 2.f*p - xxi - xx[bbase + jj];
    const u32 s = __float_as_uint(d);
    const u32 k32 = (s & 0x80000000u) ? ~s : (s | 0x80000000u);
    u64 key = ((u64)k32 << 32) | (u64)(0xFFFFFFFFu - (u32)jj);
    if (!valid) key = 0ULL;
#pragma unroll
    for (int qq = KK-1; qq >= 1; --qq) {
      const u64 mn = (kv[qq-1] < key) ? kv[qq-1] : key;
      if (kv[qq] < mn) kv[qq] = mn;
    }
    if (kv[0] < key) kv[0] = key;
  }
  if (g == 0) {
#pragma unroll
    for (int k = 0; k < KK; ++k)
      idxo[(size_t)rowg*KK + k] = (int)(0xFFFFFFFFu - (u32)(kv[k] & 0xFFFFFFFFu));
  }
}

// ---------------- K3: gather neighbors, per-(b,n,o) max/min of h, BN sums
__global__ __launch_bounds__(256) void k3_gather(
    const float* __restrict__ p1, const float* __restrict__ p2,
    const int* __restrict__ idx, float* __restrict__ maxh,
    float* __restrict__ minh, double* __restrict__ sums) {
  const int t = threadIdx.x;
  const int g = t >> 6, o = t & 63;
  const int L = blockIdx.x;
  const int bbase = (L & 7) * NN;
  const int pn0 = bbase + (L >> 3)*64 + g*16;
  float sacc = 0.f, ssacc = 0.f;

  for (int p = 0; p < 16; ++p) {
    const int pn = pn0 + p;
    const float p1v = p1[(size_t)pn*64 + o];
    const int* ip = idx + (size_t)pn*KK;
    float mx = -INFINITY, mn = INFINITY;
#pragma unroll
    for (int k = 0; k < KK; ++k) {
      const int j = ip[k];
      const float p2v = p2[((size_t)(bbase + j))*64 + o];
      const float h = p1v + p2v;
      mx = fmaxf(mx, h); mn = fminf(mn, h);
      sacc += h; ssacc += h*h;
    }
    maxh[(size_t)pn*64 + o] = mx;
    minh[(size_t)pn*64 + o] = mn;
  }

  __shared__ float rs[256], rss[256];
  rs[t] = sacc; rss[t] = ssacc;
  __syncthreads();
  if (t < 64) {
    const double sv  = (double)rs[t]  + (double)rs[t+64]  + (double)rs[t+128]  + (double)rs[t+192];
    const double ssv = (double)rss[t] + (double)rss[t+64] + (double)rss[t+128] + (double)rss[t+192];
    atomicAdd(&sums[t], sv);
    atomicAdd(&sums[64 + t], ssv);
  }
}

// ---------------- K4: finalize BN, activation, transpose to (b,o,n)
__global__ __launch_bounds__(256) void k4_out(
    const float* __restrict__ maxh, const float* __restrict__ minh,
    const double* __restrict__ sums, const float* __restrict__ gamma,
    const float* __restrict__ beta, float* __restrict__ out) {
  __shared__ float sc_[64], sh_[64];
  __shared__ float lmax[64*65], lmin[64*65];
  const int b  = blockIdx.y;
  const int n0 = blockIdx.x * 64;
  const int t  = threadIdx.x;

  if (t < 64) {
    const double mean = sums[t] / CNT_TOTAL;
    const double var  = sums[64 + t] / CNT_TOTAL - mean*mean;
    const float scale = gamma[t] * (float)(1.0 / sqrt(var + EPSV));
    sc_[t] = scale;
    sh_[t] = beta[t] - (float)mean * scale;
  }
#pragma unroll
  for (int r = 0; r < 16; ++r) {
    const int linear = r*256 + t;
    const int o = linear & 63, pos = linear >> 6;
    const size_t gg = ((size_t)(b*NN) + n0 + pos)*64 + o;
    lmax[o*65 + pos] = maxh[gg];
    lmin[o*65 + pos] = minh[gg];
  }
  __syncthreads();

  const int nn = t & 63;
  const int obase = (t >> 6) * 16;
#pragma unroll
  for (int r = 0; r < 16; ++r) {
    const int o = obase + r;
    const float scale = sc_[o], shift = sh_[o];
    const float src = (scale >= 0.f) ? lmax[o*65 + nn] : lmin[o*65 + nn];
    float v = scale*src + shift;
    v = (v >= 0.f) ? v : NEG_SLOPE*v;
    out[(size_t)b*CO*NN + (size_t)o*NN + n0 + nn] = v;
  }
}

extern "C" void kernel_launch(void* const* d_in, const int* in_sizes, int n_in,
                              void* d_out, int out_size, void* d_ws, size_t ws_size,
                              hipStream_t stream) {
  const float* x     = (const float*)d_in[0];
  const float* W     = (const float*)d_in[1];
  const float* gamma = (const float*)d_in[2];
  const float* beta  = (const float*)d_in[3];
  float* out = (float*)d_out;
  char* ws = (char*)d_ws;

  float*  p1   = (float*)(ws + OFF_P1);
  float*  p2   = (float*)(ws + OFF_P2);
  float*  xx   = (float*)(ws + OFF_XX);
  int*    idx  = (int*)  (ws + OFF_IDX);
  float*  XT   = (float*)(ws + OFF_XT);
  U16*    XB   = (U16*)  (ws + OFF_XB);
  float*  TV   = (float*)(ws + OFF_TV);
  float*  thr  = (float*)(ws + OFF_THR);
  int*    cand = (int*)  (ws + OFF_CAND);
  int*    ccnt = (int*)  (ws + OFF_CCNT);
  float*  maxh = (float*)(ws + OFF_MAXH);
  float*  minh = (float*)(ws + OFF_MINH);
  double* sums = (double*)(ws + OFF_SUMS);

  // CCNT and SUMS are adjacent: one memset
  hipMemsetAsync(ws + OFF_CCNT, 0, (OFF_SUMS - OFF_CCNT) + 1024, stream);

  k0_repack <<<dim3(NN/64, BB), 256, 0, stream>>>(x, XT, XB);
  k1_project<<<dim3(NN/64, BB), 256, 0, stream>>>(x, W, p1, p2, xx);
  k2ab<0>   <<<dim3(1024), 256, 0, stream>>>(XB, xx, TV, thr, ccnt, cand);
  k2b_thr   <<<dim3(BN/256), 256, 0, stream>>>(TV, thr);
  k2ab<1>   <<<dim3(1024), 256, 0, stream>>>(XB, xx, TV, thr, ccnt, cand);
  k2e_exact <<<dim3(BN/64), 256, 0, stream>>>(XT, xx, ccnt, cand, idx);
  k3_gather <<<dim3(BN/64), 256, 0, stream>>>(p1, p2, idx, maxh, minh, sums);
  k4_out    <<<dim3(NN/64, BB), 256, 0, stream>>>(maxh, minh, sums, gamma, beta, out);
}